// Round 1
// 104.166 us; speedup vs baseline: 1.0360x; 1.0360x over previous
//
#include <hip/hip_runtime.h>
#include <math.h>

constexpr int B_ = 4, C_ = 32, L_ = 256, M_ = 256, F_ = 8, N_ = 64;

// One (b,l) per 256-thread block (4 waves). Wave w: c-half = w&1 (16 c's),
// m-half = w>>1 (128 m's); lane owns m = mhalf*128 + lane*2 (float2 loads,
// 512B per wave-instruction, fully coalesced). Per-wave regs: 16c*2*float2
// = 64 data + 8f*2*float2 = 32 acc  ->  ~115 VGPR  ->  4 waves/SIMD via
// __launch_bounds__(256,4): 4 blocks/CU = 16 waves/CU (2x the previous 8).
// Symmetric cross-wave reduce: even wave exports acci, odd exports accr;
// even wave stores real(+relu), odd stores imag -> every wave issues stores.
__global__ __launch_bounds__(256, 4) void sphereconv_kernel(
    const float* __restrict__ xr, const float* __restrict__ xi,
    const float* __restrict__ wr, const float* __restrict__ wi,
    float* __restrict__ out)
{
    __shared__ float  ws[C_ * 16];        // interpolated weights [c][wr f0..7 | wi f0..7]
    __shared__ float2 red[4 * F_ * 64];   // per-wave export: [wave][f][lane]

    const int b     = blockIdx.x >> 8;        // / L_
    const int l     = blockIdx.x & (L_ - 1);
    const int tid   = threadIdx.x;            // 0..255
    const int wave  = tid >> 6;
    const int lane  = tid & 63;
    const int chalf = wave & 1;
    const int mhalf = wave >> 1;

    // interp coords (uniform): t = l/(L-1)*(N-1)
    const float tc = ((float)l / (float)(L_ - 1)) * (float)(N_ - 1);
    int lo = (int)floorf(tc);
    if (lo > N_ - 2) lo = N_ - 2;
    const float frac = tc - (float)lo;

    // stage 512 interpolated weight floats: 2 per thread
#pragma unroll
    for (int i = tid; i < C_ * 16; i += 256) {
        const int c = i >> 4;
        const int j = i & 15;
        const int f = j & 7;
        const float* w = (j & 8) ? wi : wr;
        const int base = (f * C_ + c) * N_ + lo;   // w layout (F,C,N,1)
        ws[c * 16 + j] = w[base] * (1.0f - frac) + w[base + 1] * frac;
    }
    __syncthreads();

    const int c0 = chalf * 16;
    const int m  = mhalf * 128 + lane * 2;
    const size_t strideC2 = (size_t)L_ * M_ / 2;   // c-stride in float2 units
    const size_t xoff = ((size_t)b * C_ + c0) * (size_t)L_ * M_ + (size_t)l * M_ + m;
    const float2* xr2 = (const float2*)(xr + xoff);
    const float2* xi2 = (const float2*)(xi + xoff);

    // ---- preload phase: issue all 32 row loads before any consumption ----
    float2 xv_r[16], xv_i[16];
#pragma unroll
    for (int c = 0; c < 16; ++c) {
        xv_r[c] = xr2[c * strideC2];
        xv_i[c] = xi2[c * strideC2];
    }

    float2 accr[F_], acci[F_];
#pragma unroll
    for (int f = 0; f < F_; ++f) {
        accr[f] = make_float2(0.f, 0.f);
        acci[f] = make_float2(0.f, 0.f);
    }

#define CX(f, A, Bv)                                          \
    accr[f].x = fmaf(A, vr.x, fmaf(-(Bv), vi.x, accr[f].x));  \
    accr[f].y = fmaf(A, vr.y, fmaf(-(Bv), vi.y, accr[f].y));  \
    acci[f].x = fmaf(A, vi.x, fmaf((Bv), vr.x, acci[f].x));   \
    acci[f].y = fmaf(A, vi.y, fmaf((Bv), vr.y, acci[f].y));

    // ---- compute phase ----
#pragma unroll
    for (int c = 0; c < 16; ++c) {
        const float2 vr = xv_r[c];
        const float2 vi = xv_i[c];
        const float* wp = &ws[(c0 + c) * 16];
        const float4 a0 = *(const float4*)(wp + 0);   // wr f0..3 (LDS broadcast)
        const float4 a1 = *(const float4*)(wp + 4);   // wr f4..7
        const float4 b0 = *(const float4*)(wp + 8);   // wi f0..3
        const float4 b1 = *(const float4*)(wp + 12);  // wi f4..7
        CX(0, a0.x, b0.x)
        CX(1, a0.y, b0.y)
        CX(2, a0.z, b0.z)
        CX(3, a0.w, b0.w)
        CX(4, a1.x, b1.x)
        CX(5, a1.y, b1.y)
        CX(6, a1.z, b1.z)
        CX(7, a1.w, b1.w)
    }
#undef CX

    // ---- symmetric export: even wave -> acci, odd wave -> accr ----
    {
        float2* myexp = &red[wave * F_ * 64];
#pragma unroll
        for (int f = 0; f < F_; ++f)
            myexp[f * 64 + lane] = (wave & 1) ? accr[f] : acci[f];
    }
    __syncthreads();

    // ---- combine + epilogue: even wave owns real(+relu), odd owns imag ----
    const float scale = sqrtf(1.0f + (float)l) * (1.0f / (float)C_);
    const size_t fStride = (size_t)L_ * M_;
    // out layout: (((s*B + b)*F + f)*L + l)*M + m ; s=0 real(relu), s=1 imag
    const size_t o0 = (((size_t)b * F_) * (size_t)L_ + l) * M_ + m;
    if ((wave & 1) == 0) {
        const float2* pr = &red[(wave + 1) * F_ * 64];   // partner's accr
#pragma unroll
        for (int f = 0; f < F_; ++f) {
            const float2 p = pr[f * 64 + lane];
            float2 y;
            y.x = fmaxf((accr[f].x + p.x) * scale, 0.f);
            y.y = fmaxf((accr[f].y + p.y) * scale, 0.f);
            *(float2*)(out + o0 + (size_t)f * fStride) = y;
        }
    } else {
        const size_t imagOff = (size_t)B_ * F_ * L_ * M_;
        const float2* pi = &red[(wave - 1) * F_ * 64];   // partner's acci
#pragma unroll
        for (int f = 0; f < F_; ++f) {
            const float2 p = pi[f * 64 + lane];
            float2 y;
            y.x = (acci[f].x + p.x) * scale;
            y.y = (acci[f].y + p.y) * scale;
            *(float2*)(out + o0 + (size_t)f * fStride + imagOff) = y;
        }
    }
}

extern "C" void kernel_launch(void* const* d_in, const int* in_sizes, int n_in,
                              void* d_out, int out_size, void* d_ws, size_t ws_size,
                              hipStream_t stream) {
    const float* xr = (const float*)d_in[0];
    const float* xi = (const float*)d_in[1];
    const float* wr = (const float*)d_in[2];
    const float* wi = (const float*)d_in[3];
    float* out = (float*)d_out;
    sphereconv_kernel<<<dim3(B_ * L_), dim3(256), 0, stream>>>(xr, xi, wr, wi, out);
}